// Round 1
// 590.186 us; speedup vs baseline: 1.5379x; 1.5379x over previous
//
#include <hip/hip_runtime.h>

#define GLOBAL_AS __attribute__((address_space(1)))
#define LDS_AS    __attribute__((address_space(3)))

typedef short bf16x8 __attribute__((ext_vector_type(8)));
typedef float f32x4  __attribute__((ext_vector_type(4)));

// Problem shape (fixed by setup_inputs)
#define M_DIM 8192     // B*S = 4*2048
#define N_DIM 4096     // DOUT
#define K_DIM 4096     // DIN
#define R_DIM 16
#define KAUG  4224     // 66 K-tiles of 64: 4096 data + 16 lora + 112 zeros

__constant__ float NF4C[16] = {
    -1.0f, -0.6961928009986877f, -0.5250730514526367f, -0.39491748809814453f,
    -0.28444138169288635f, -0.18477343022823334f, -0.09105003625154495f, 0.0f,
    0.07958029955625534f, 0.16093020141124725f, 0.24611230194568634f,
    0.33791524171829224f, 0.44070982933044434f, 0.5626170039176941f,
    0.7229568362236023f, 1.0f};

__device__ __forceinline__ unsigned short f2bf(float f) {
    unsigned int u = __float_as_uint(f);
    u += 0x7fffu + ((u >> 16) & 1u);   // round-to-nearest-even
    return (unsigned short)(u >> 16);
}

// ---- prep A: x fp32 -> bf16 (cols 0..4095) + fused lora_a dot (cols 4096..4111),
// zeros to 4223. No LDS; A (256KB) is L2-resident, read as fp32 directly.
// NOTE: no runtime indexing into acc[] anywhere (keeps it in VGPRs, rule #20).
__global__ __launch_bounds__(256) void prep_x_kernel(
        const float4* __restrict__ x4, const float4* __restrict__ A4,
        unsigned short* __restrict__ xb) {
    const int tid = threadIdx.x;
    const int wave = tid >> 6, lane = tid & 63;
    const int m = blockIdx.x * 4 + wave;
    const float4* xrow = x4 + (size_t)m * 1024;
    unsigned short* xbrow = xb + (size_t)m * KAUG;
    float acc[16];
#pragma unroll
    for (int r = 0; r < 16; ++r) acc[r] = 0.0f;
    for (int ii = 0; ii < 16; ++ii) {
        const int k4 = lane + ii * 64;
        float4 xv = xrow[k4];
        ushort4 o;
        o.x = f2bf(xv.x); o.y = f2bf(xv.y); o.z = f2bf(xv.z); o.w = f2bf(xv.w);
        *(ushort4*)(xbrow + k4 * 4) = o;
#pragma unroll
        for (int r = 0; r < 16; ++r) {
            float4 av = A4[r * 1024 + k4];
            acc[r] += xv.x * av.x + xv.y * av.y + xv.z * av.z + xv.w * av.w;
        }
    }
#pragma unroll
    for (int r = 0; r < 16; ++r) {
#pragma unroll
        for (int off = 32; off; off >>= 1)
            acc[r] += __shfl_xor(acc[r], off, 64);
    }
    // extract acc[lane] WITHOUT dynamic indexing: cndmask chain
    float v = 0.0f;
#pragma unroll
    for (int r = 0; r < 16; ++r) v = (lane == r) ? acc[r] : v;
    xbrow[K_DIM + lane]      = (lane < 16) ? f2bf(v) : (unsigned short)0;
    xbrow[K_DIM + 64 + lane] = 0;   // zero pad cols 4160..4223
}

// ---- prep B: NF4 dequant -> wq cols 0..4095; threads k4<32 fill lora+zero tail
__global__ __launch_bounds__(256) void dequant_kernel(
        const int4* __restrict__ codes4, const float* __restrict__ absmax,
        const float* __restrict__ loraB, unsigned short* __restrict__ wq) {
    const int idx = blockIdx.x * 256 + threadIdx.x;   // int4 index
    const int n = idx >> 10;
    const int k4 = idx & 1023;
    const float am = absmax[n * 64 + (k4 >> 4)];
    int4 c = codes4[idx];
    ushort4 o;
    o.x = f2bf(NF4C[c.x] * am);
    o.y = f2bf(NF4C[c.y] * am);
    o.z = f2bf(NF4C[c.z] * am);
    o.w = f2bf(NF4C[c.w] * am);
    *(ushort4*)(wq + (size_t)n * KAUG + k4 * 4) = o;
    if (k4 < 32) {   // cols 4096..4223: 16x 2*loraB then zeros
        ushort4 l = {0, 0, 0, 0};
        if (k4 < 4) {
            const int c0 = k4 * 4;
            l.x = f2bf(2.0f * loraB[n * R_DIM + c0 + 0]);
            l.y = f2bf(2.0f * loraB[n * R_DIM + c0 + 1]);
            l.z = f2bf(2.0f * loraB[n * R_DIM + c0 + 2]);
            l.w = f2bf(2.0f * loraB[n * R_DIM + c0 + 3]);
        }
        *(ushort4*)(wq + (size_t)n * KAUG + K_DIM + k4 * 4) = l;
    }
}

// ---- main GEMM: 256x256 tile, BK=64, 8 waves (2M x 4N), 8-phase counted-vmcnt
// LDS 128KB: A[2dbuf][2kh][256][32] at 0, B same at 32768 (shorts).
// Swizzle: 16B-chunk c ^= (row>>1)&3 within 64B rows -> 2-way (free) ds_read_b128.
// Stage order (tile t, buf d=t&1): ph0: t+1 A-kh1 | ph1: t+2 B-kh0 |
//   ph2: t+2 A-kh0 | ph3: t+2 B-kh1 + vmcnt(6). Steady state: 3 half-tiles in
//   flight; vmcnt(6) at tile boundary retires ALL of tile t+1 (verified by queue
//   order: newest 6 loads are t+2's). Region reuse safe: each target region's
//   reads complete >=1 barrier before its overwrite.
#define STG(gptr, ldsoff)                                                   \
    __builtin_amdgcn_global_load_lds((const GLOBAL_AS void*)(gptr),         \
                                     (LDS_AS void*)(smem + (ldsoff)), 16, 0, 0)
#define STAGE_A(d, kh, kt) do {                                             \
    STG(gA + (size_t)(kt) * 64 + (kh) * 32,                                 \
        (d) * 16384 + (kh) * 8192 + wave * 512);                            \
    STG(gA + (size_t)128 * KAUG + (size_t)(kt) * 64 + (kh) * 32,            \
        (d) * 16384 + (kh) * 8192 + 4096 + wave * 512); } while (0)
#define STAGE_B(d, kh, kt) do {                                             \
    STG(gB + (size_t)(kt) * 64 + (kh) * 32,                                 \
        32768 + (d) * 16384 + (kh) * 8192 + wave * 512);                    \
    STG(gB + (size_t)128 * KAUG + (size_t)(kt) * 64 + (kh) * 32,            \
        32768 + (d) * 16384 + (kh) * 8192 + 4096 + wave * 512); } while (0)
#define NOPX ((void)0)
#define VMCNT6 asm volatile("s_waitcnt vmcnt(6)" ::: "memory")
#define VMCNT0 asm volatile("s_waitcnt vmcnt(0)" ::: "memory")

#define PHASE(d, kh, mig, STAGE_STMT, VM_STMT) do {                         \
    bf16x8 af[4];                                                           \
    _Pragma("unroll")                                                       \
    for (int i_ = 0; i_ < 4; ++i_)                                          \
        af[i_] = *(const bf16x8*)(smem + (d) * 16384 + (kh) * 8192 + aoff + \
                                  ((mig) * 4 + i_) * 512);                  \
    if ((mig) == 0) {                                                       \
        _Pragma("unroll")                                                   \
        for (int j_ = 0; j_ < 4; ++j_)                                      \
            bfr[j_] = *(const bf16x8*)(smem + (d) * 16384 + (kh) * 8192 +   \
                                       boff + j_ * 512);                    \
    }                                                                       \
    STAGE_STMT;                                                             \
    __builtin_amdgcn_s_barrier();                                           \
    asm volatile("s_waitcnt lgkmcnt(0)" ::: "memory");                      \
    __builtin_amdgcn_sched_barrier(0);                                      \
    __builtin_amdgcn_s_setprio(1);                                          \
    _Pragma("unroll")                                                       \
    for (int i_ = 0; i_ < 4; ++i_)                                          \
        _Pragma("unroll")                                                   \
        for (int j_ = 0; j_ < 4; ++j_)                                      \
            acc[(mig) * 4 + i_][j_] = __builtin_amdgcn_mfma_f32_16x16x32_bf16( \
                af[i_], bfr[j_], acc[(mig) * 4 + i_][j_], 0, 0, 0);         \
    __builtin_amdgcn_s_setprio(0);                                          \
    VM_STMT;                                                                \
    __builtin_amdgcn_s_barrier();                                           \
} while (0)

__global__ __launch_bounds__(512) void gemm_kernel(
        const unsigned short* __restrict__ xb,
        const unsigned short* __restrict__ wq,
        float* __restrict__ out) {
    __shared__ __align__(16) unsigned short smem[65536];   // 128 KiB
    const int tid = threadIdx.x;
    const int wave = tid >> 6, lane = tid & 63;

    // XCD-aware swizzle over 512 blocks (16 n-tiles x 32 m-tiles); 512%8==0
    const int bid = blockIdx.y * 16 + blockIdx.x;
    const int swz = (bid & 7) * 64 + (bid >> 3);
    const int m0 = (swz >> 4) * 256;
    const int n0 = (swz & 15) * 256;

    // staging: thread covers row 16*wave + (lane>>2), swizzled 16B chunk
    const int schunk = ((lane & 3) ^ ((lane >> 3) & 3)) * 8;
    const unsigned short* gA =
        xb + (size_t)(m0 + wave * 16 + (lane >> 2)) * KAUG + schunk;
    const unsigned short* gB =
        wq + (size_t)(n0 + wave * 16 + (lane >> 2)) * KAUG + schunk;

    // fragment read bases
    const int wr = wave >> 2, wc = wave & 3;
    const int fm = lane & 15, q = lane >> 4;
    const int rk = (q ^ ((fm >> 1) & 3)) * 8;          // swizzled chunk (shorts)
    const int aoff = wr * 4096 + fm * 32 + rk;         // + d*16384 + kh*8192 + mi*512
    const int boff = 32768 + wc * 2048 + fm * 32 + rk; // + d*16384 + kh*8192 + ni*512

    f32x4 acc[8][4] = {};
    bf16x8 bfr[4];

    // prologue: t0 {A0,B0,A1,B1}, t1 {B0,A0,B1}; vmcnt(6) -> t0 fully landed
    STAGE_A(0, 0, 0); STAGE_B(0, 0, 0); STAGE_A(0, 1, 0); STAGE_B(0, 1, 0);
    STAGE_B(1, 0, 1); STAGE_A(1, 0, 1); STAGE_B(1, 1, 1);
    VMCNT6;
    __builtin_amdgcn_s_barrier();

#pragma unroll 1
    for (int kt = 0; kt < 64; kt += 2) {
        // tile kt (buf0)
        PHASE(0, 0, 0, STAGE_A(1, 1, kt + 1), NOPX);
        PHASE(0, 0, 1, STAGE_B(0, 0, kt + 2), NOPX);
        PHASE(0, 1, 0, STAGE_A(0, 0, kt + 2), NOPX);
        PHASE(0, 1, 1, STAGE_B(0, 1, kt + 2), VMCNT6);
        // tile kt+1 (buf1)
        PHASE(1, 0, 0, STAGE_A(0, 1, kt + 2), NOPX);
        PHASE(1, 0, 1, STAGE_B(1, 0, kt + 3), NOPX);
        PHASE(1, 1, 0, STAGE_A(1, 0, kt + 3), NOPX);
        PHASE(1, 1, 1, STAGE_B(1, 1, kt + 3), VMCNT6);
    }
    // tile 64 (buf0): only t65 A-kh1 left to stage; drain before last tile
    PHASE(0, 0, 0, STAGE_A(1, 1, 65), NOPX);
    PHASE(0, 0, 1, NOPX, NOPX);
    PHASE(0, 1, 0, NOPX, NOPX);
    PHASE(0, 1, 1, NOPX, VMCNT0);
    // tile 65 (buf1): no stages
    PHASE(1, 0, 0, NOPX, NOPX);
    PHASE(1, 0, 1, NOPX, NOPX);
    PHASE(1, 1, 0, NOPX, NOPX);
    PHASE(1, 1, 1, NOPX, NOPX);

    // epilogue: C/D layout col=lane&15, row=(lane>>4)*4+reg
    const int col0 = n0 + wc * 64 + fm;
    const int row0 = m0 + wr * 128 + q * 4;
#pragma unroll
    for (int mi = 0; mi < 8; ++mi)
#pragma unroll
        for (int ni = 0; ni < 4; ++ni)
#pragma unroll
            for (int r = 0; r < 4; ++r)
                out[(size_t)(row0 + mi * 16 + r) * N_DIM + col0 + ni * 16] =
                    acc[mi][ni][r];
}

extern "C" void kernel_launch(void* const* d_in, const int* in_sizes, int n_in,
                              void* d_out, int out_size, void* d_ws, size_t ws_size,
                              hipStream_t stream) {
    const float* x      = (const float*)d_in[0];
    const int*   codes  = (const int*)d_in[1];
    const float* absmax = (const float*)d_in[2];
    const float* loraA  = (const float*)d_in[3];
    const float* loraB  = (const float*)d_in[4];
    float* out = (float*)d_out;

    unsigned short* xb = (unsigned short*)d_ws;            // [8192][4224] bf16
    unsigned short* wq = xb + (size_t)M_DIM * KAUG;        // [4096][4224] bf16 (~103.8 MB total)

    prep_x_kernel<<<M_DIM / 4, 256, 0, stream>>>((const float4*)x,
                                                 (const float4*)loraA, xb);
    dequant_kernel<<<(N_DIM * K_DIM / 4) / 256, 256, 0, stream>>>(
        (const int4*)codes, absmax, loraB, wq);

    dim3 grid(N_DIM / 256, M_DIM / 256);   // 16 x 32
    gemm_kernel<<<grid, 512, 0, stream>>>(xb, wq, out);
}

// Round 2
// 545.445 us; speedup vs baseline: 1.6640x; 1.0820x over previous
//
#include <hip/hip_runtime.h>

#define GLOBAL_AS __attribute__((address_space(1)))
#define LDS_AS    __attribute__((address_space(3)))

typedef short bf16x8 __attribute__((ext_vector_type(8)));
typedef float f32x4  __attribute__((ext_vector_type(4)));

// Problem shape (fixed by setup_inputs)
#define M_DIM 8192     // B*S = 4*2048
#define N_DIM 4096     // DOUT
#define K_DIM 4096     // DIN  (no augmentation: lora folded into weights)
#define R_DIM 16

__constant__ float NF4C[16] = {
    -1.0f, -0.6961928009986877f, -0.5250730514526367f, -0.39491748809814453f,
    -0.28444138169288635f, -0.18477343022823334f, -0.09105003625154495f, 0.0f,
    0.07958029955625534f, 0.16093020141124725f, 0.24611230194568634f,
    0.33791524171829224f, 0.44070982933044434f, 0.5626170039176941f,
    0.7229568362236023f, 1.0f};

__device__ __forceinline__ unsigned short f2bf(float f) {
    unsigned int u = __float_as_uint(f);
    u += 0x7fffu + ((u >> 16) & 1u);   // round-to-nearest-even
    return (unsigned short)(u >> 16);
}

// ---- prep A: pure streaming convert x fp32 -> bf16 (no lora work here) ----
__global__ __launch_bounds__(256) void prep_x_kernel(
        const float4* __restrict__ x4, unsigned short* __restrict__ xb) {
    const int idx = blockIdx.x * 256 + threadIdx.x;   // float4 index, 8192*1024
    float4 v = x4[idx];
    ushort4 o;
    o.x = f2bf(v.x); o.y = f2bf(v.y); o.z = f2bf(v.z); o.w = f2bf(v.w);
    *(ushort4*)(xb + (size_t)idx * 4) = o;
}

// ---- prep B: NF4 dequant + rank-16 fold: wq = bf16( NF4[c]*absmax + 2*B*A ) ----
// Block covers 256 consecutive int4s within ONE n-row (1024 int4/row) -> n is
// block-uniform, loraB loads broadcast. A-slices are L1/L2-resident (256 KB).
// All local-array indexing is compile-time (full unroll) -> stays in VGPRs.
__global__ __launch_bounds__(256) void dequant_kernel(
        const int4* __restrict__ codes4, const float* __restrict__ absmax,
        const float4* __restrict__ loraB4, const float4* __restrict__ A4,
        unsigned short* __restrict__ wq) {
    const int idx = blockIdx.x * 256 + threadIdx.x;   // int4 index, 4096*1024
    const int n = idx >> 10;
    const int k4 = idx & 1023;
    const float am = absmax[n * 64 + (k4 >> 4)];
    int4 c = codes4[idx];
    float4 b[4];
#pragma unroll
    for (int j = 0; j < 4; ++j) b[j] = loraB4[n * 4 + j];
    float bax = 0.f, bay = 0.f, baz = 0.f, baw = 0.f;
#pragma unroll
    for (int r = 0; r < 16; ++r) {
        const float br = (r & 2) ? ((r & 1) ? b[r >> 2].w : b[r >> 2].z)
                                 : ((r & 1) ? b[r >> 2].y : b[r >> 2].x);
        float4 av = A4[r * 1024 + k4];
        bax += br * av.x; bay += br * av.y; baz += br * av.z; baw += br * av.w;
    }
    ushort4 o;
    o.x = f2bf(NF4C[c.x] * am + 2.0f * bax);
    o.y = f2bf(NF4C[c.y] * am + 2.0f * bay);
    o.z = f2bf(NF4C[c.z] * am + 2.0f * baz);
    o.w = f2bf(NF4C[c.w] * am + 2.0f * baw);
    *(ushort4*)(wq + (size_t)n * K_DIM + k4 * 4) = o;
}

// ---- main GEMM: 256x256 tile, BK=64, 8 waves (2M x 4N), 8-phase counted-vmcnt
// LDS 128KB: A[2dbuf][2kh][256][32] at 0, B same at 32768 (shorts).
// Swizzle: 16B-chunk c ^= (row>>1)&3 within 64B rows -> 2-way (free) ds_read_b128.
// Stage order (tile t, buf d=t&1): ph0: t+1 A-kh1 | ph1: t+2 B-kh0 |
//   ph2: t+2 A-kh0 | ph3: t+2 B-kh1 + vmcnt(6). Steady state: 3 half-tiles in
//   flight; vmcnt(6) at tile boundary retires ALL of tile t+1 (queue order:
//   newest 6 loads are t+2's). Region reuse safe: each target region's reads
//   complete >=1 barrier before its overwrite.
#define STG(gptr, ldsoff)                                                   \
    __builtin_amdgcn_global_load_lds((const GLOBAL_AS void*)(gptr),         \
                                     (LDS_AS void*)(smem + (ldsoff)), 16, 0, 0)
#define STAGE_A(d, kh, kt) do {                                             \
    STG(gA + (size_t)(kt) * 64 + (kh) * 32,                                 \
        (d) * 16384 + (kh) * 8192 + wave * 512);                            \
    STG(gA + (size_t)128 * K_DIM + (size_t)(kt) * 64 + (kh) * 32,           \
        (d) * 16384 + (kh) * 8192 + 4096 + wave * 512); } while (0)
#define STAGE_B(d, kh, kt) do {                                             \
    STG(gB + (size_t)(kt) * 64 + (kh) * 32,                                 \
        32768 + (d) * 16384 + (kh) * 8192 + wave * 512);                    \
    STG(gB + (size_t)128 * K_DIM + (size_t)(kt) * 64 + (kh) * 32,           \
        32768 + (d) * 16384 + (kh) * 8192 + 4096 + wave * 512); } while (0)
#define NOPX ((void)0)
#define VMCNT6 asm volatile("s_waitcnt vmcnt(6)" ::: "memory")
#define VMCNT0 asm volatile("s_waitcnt vmcnt(0)" ::: "memory")

#define PHASE(d, kh, mig, STAGE_STMT, VM_STMT) do {                         \
    bf16x8 af[4];                                                           \
    _Pragma("unroll")                                                       \
    for (int i_ = 0; i_ < 4; ++i_)                                          \
        af[i_] = *(const bf16x8*)(smem + (d) * 16384 + (kh) * 8192 + aoff + \
                                  ((mig) * 4 + i_) * 512);                  \
    if ((mig) == 0) {                                                       \
        _Pragma("unroll")                                                   \
        for (int j_ = 0; j_ < 4; ++j_)                                      \
            bfr[j_] = *(const bf16x8*)(smem + (d) * 16384 + (kh) * 8192 +   \
                                       boff + j_ * 512);                    \
    }                                                                       \
    STAGE_STMT;                                                             \
    __builtin_amdgcn_s_barrier();                                           \
    asm volatile("s_waitcnt lgkmcnt(0)" ::: "memory");                      \
    __builtin_amdgcn_sched_barrier(0);                                      \
    __builtin_amdgcn_s_setprio(1);                                          \
    _Pragma("unroll")                                                       \
    for (int i_ = 0; i_ < 4; ++i_)                                          \
        _Pragma("unroll")                                                   \
        for (int j_ = 0; j_ < 4; ++j_)                                      \
            acc[(mig) * 4 + i_][j_] = __builtin_amdgcn_mfma_f32_16x16x32_bf16( \
                af[i_], bfr[j_], acc[(mig) * 4 + i_][j_], 0, 0, 0);         \
    __builtin_amdgcn_s_setprio(0);                                          \
    VM_STMT;                                                                \
    __builtin_amdgcn_s_barrier();                                           \
} while (0)

__global__ __launch_bounds__(512) void gemm_kernel(
        const unsigned short* __restrict__ xb,
        const unsigned short* __restrict__ wq,
        float* __restrict__ out) {
    __shared__ __align__(16) unsigned short smem[65536];   // 128 KiB
    const int tid = threadIdx.x;
    const int wave = tid >> 6, lane = tid & 63;

    // XCD-aware swizzle over 512 blocks (16 n-tiles x 32 m-tiles); 512%8==0
    const int bid = blockIdx.y * 16 + blockIdx.x;
    const int swz = (bid & 7) * 64 + (bid >> 3);
    const int m0 = (swz >> 4) * 256;
    const int n0 = (swz & 15) * 256;

    // staging: thread covers row 16*wave + (lane>>2), swizzled 16B chunk
    const int schunk = ((lane & 3) ^ ((lane >> 3) & 3)) * 8;
    const unsigned short* gA =
        xb + (size_t)(m0 + wave * 16 + (lane >> 2)) * K_DIM + schunk;
    const unsigned short* gB =
        wq + (size_t)(n0 + wave * 16 + (lane >> 2)) * K_DIM + schunk;

    // fragment read bases
    const int wr = wave >> 2, wc = wave & 3;
    const int fm = lane & 15, q = lane >> 4;
    const int rk = (q ^ ((fm >> 1) & 3)) * 8;          // swizzled chunk (shorts)
    const int aoff = wr * 4096 + fm * 32 + rk;         // + d*16384 + kh*8192 + mi*512
    const int boff = 32768 + wc * 2048 + fm * 32 + rk; // + d*16384 + kh*8192 + ni*512

    f32x4 acc[8][4] = {};
    bf16x8 bfr[4];

    // prologue: t0 {A0,B0,A1,B1}, t1 {B0,A0,B1}; vmcnt(6) -> t0 fully landed
    STAGE_A(0, 0, 0); STAGE_B(0, 0, 0); STAGE_A(0, 1, 0); STAGE_B(0, 1, 0);
    STAGE_B(1, 0, 1); STAGE_A(1, 0, 1); STAGE_B(1, 1, 1);
    VMCNT6;
    __builtin_amdgcn_s_barrier();

#pragma unroll 1
    for (int kt = 0; kt < 62; kt += 2) {
        // tile kt (buf0)
        PHASE(0, 0, 0, STAGE_A(1, 1, kt + 1), NOPX);
        PHASE(0, 0, 1, STAGE_B(0, 0, kt + 2), NOPX);
        PHASE(0, 1, 0, STAGE_A(0, 0, kt + 2), NOPX);
        PHASE(0, 1, 1, STAGE_B(0, 1, kt + 2), VMCNT6);
        // tile kt+1 (buf1)
        PHASE(1, 0, 0, STAGE_A(0, 1, kt + 2), NOPX);
        PHASE(1, 0, 1, STAGE_B(1, 0, kt + 3), NOPX);
        PHASE(1, 1, 0, STAGE_A(1, 0, kt + 3), NOPX);
        PHASE(1, 1, 1, STAGE_B(1, 1, kt + 3), VMCNT6);
    }
    // tile 62 (buf0): only t63 A-kh1 left to stage; drain before last tile
    PHASE(0, 0, 0, STAGE_A(1, 1, 63), NOPX);
    PHASE(0, 0, 1, NOPX, NOPX);
    PHASE(0, 1, 0, NOPX, NOPX);
    PHASE(0, 1, 1, NOPX, VMCNT0);
    // tile 63 (buf1): no stages
    PHASE(1, 0, 0, NOPX, NOPX);
    PHASE(1, 0, 1, NOPX, NOPX);
    PHASE(1, 1, 0, NOPX, NOPX);
    PHASE(1, 1, 1, NOPX, NOPX);

    // epilogue: C/D layout col=lane&15, row=(lane>>4)*4+reg
    const int col0 = n0 + wc * 64 + fm;
    const int row0 = m0 + wr * 128 + q * 4;
#pragma unroll
    for (int mi = 0; mi < 8; ++mi)
#pragma unroll
        for (int ni = 0; ni < 4; ++ni)
#pragma unroll
            for (int r = 0; r < 4; ++r)
                out[(size_t)(row0 + mi * 16 + r) * N_DIM + col0 + ni * 16] =
                    acc[mi][ni][r];
}

extern "C" void kernel_launch(void* const* d_in, const int* in_sizes, int n_in,
                              void* d_out, int out_size, void* d_ws, size_t ws_size,
                              hipStream_t stream) {
    const float* x      = (const float*)d_in[0];
    const int*   codes  = (const int*)d_in[1];
    const float* absmax = (const float*)d_in[2];
    const float* loraA  = (const float*)d_in[3];
    const float* loraB  = (const float*)d_in[4];
    float* out = (float*)d_out;

    unsigned short* xb = (unsigned short*)d_ws;            // [8192][4096] bf16
    unsigned short* wq = xb + (size_t)M_DIM * K_DIM;       // [4096][4096] bf16 (100.7 MB total)

    prep_x_kernel<<<(M_DIM * K_DIM / 4) / 256, 256, 0, stream>>>(
        (const float4*)x, xb);
    dequant_kernel<<<(N_DIM * K_DIM / 4) / 256, 256, 0, stream>>>(
        (const int4*)codes, absmax, (const float4*)loraB, (const float4*)loraA, wq);

    dim3 grid(N_DIM / 256, M_DIM / 256);   // 16 x 32
    gemm_kernel<<<grid, 512, 0, stream>>>(xb, wq, out);
}